// Round 5
// baseline (45.910 us; speedup 1.0000x reference)
//
#include <hip/hip_runtime.h>

#define BB 16
#define NN 128
#define DD 128

// Transpose weights into float4-interleaved layout:
// WmT4[((dcol>>2)*128 + k)*4 + (dcol&3)] = Wm[k*384 + dcol]
// WuT4 same with 256 d-rows. Thread k loads 4 consecutive-d weights as one
// float4, coalesced across lanes.
__global__ __launch_bounds__(256) void wtrans_kernel(const float* __restrict__ Wm,
                                                     const float* __restrict__ Wu,
                                                     float* __restrict__ WmT4,
                                                     float* __restrict__ WuT4) {
    const int idx = blockIdx.x * 256 + threadIdx.x;
    if (idx < 384 * 128) {
        const int k = idx / 384, dcol = idx % 384;
        WmT4[((dcol >> 2) * 128 + k) * 4 + (dcol & 3)] = Wm[idx];
    } else {
        const int o = idx - 384 * 128;
        const int k = o / 256, dcol = o % 256;
        WuT4[((dcol >> 2) * 128 + k) * 4 + (dcol & 3)] = Wu[o];
    }
}

// Fused kernel. Block = (b, 4 j's), 512 threads (8 waves), 512 blocks
// -> 2 blocks/CU, 16 waves/CU while streaming (4 waves/SIMD).
// All 8 waves stream e; compute phases run on threads < 256.
__global__ __launch_bounds__(512, 4) void mpnn_kernel(
    const float* __restrict__ h, const float* __restrict__ adj,
    const float* __restrict__ e, const float* __restrict__ WmT4,
    const float* __restrict__ bm, const float* __restrict__ WuT4,
    const float* __restrict__ bu, float* __restrict__ out) {
    const int blk = blockIdx.x;
    const int b = blk >> 5;
    const int jbase = (blk & 31) * 4;
    const int t = threadIdx.x;

    __shared__ float adj_s[4][NN];
    __shared__ float h_s[4][DD];
    __shared__ float4 red[16][32];
    __shared__ float es_s[4][DD];
    __shared__ float ah_s[4][DD];
    __shared__ float ms_s[4][DD];
    __shared__ float deg_s[4];

    // ---- A: stage adj columns + h rows ----
    for (int x = t; x < 4 * NN; x += 512) {
        const int i = x >> 2, jj = x & 3;
        adj_s[jj][i] = adj[(size_t)(b * NN + i) * NN + jbase + jj];
    }
    if (t < 4 * DD) {
        const int jj = t >> 7, d0 = t & 127;
        h_s[jj][d0] = h[(size_t)(b * NN + jbase + jj) * DD + d0];
    }
    __syncthreads();

    // deg[jj] = sum_i adj[i][jj]
    if (t < 128) {
        const int jj = t >> 5, l = t & 31;
        float s = adj_s[jj][l] + adj_s[jj][l + 32] + adj_s[jj][l + 64] + adj_s[jj][l + 96];
        #pragma unroll
        for (int off = 16; off; off >>= 1) s += __shfl_xor(s, off);
        if (l == 0) deg_s[jj] = s;
    }

    // ---- B: stream e (all 8 waves). Group g of 32 lanes: jj = g&3, i-quarter = g>>2.
    {
        const int g = t >> 5, d4 = t & 31;
        const int jjB = g & 3, iq = g >> 2;
        const float4* __restrict__ e4 =
            (const float4*)e + ((size_t)b * NN * NN + (jbase + jjB)) * 32 + d4;
        float4 acc = make_float4(0.f, 0.f, 0.f, 0.f);
        const int i0 = iq * 32;
        #pragma unroll 8
        for (int ii = 0; ii < 32; ++ii) {
            const int i = i0 + ii;
            const float a = adj_s[jjB][i];
            if (a != 0.0f) {
                float4 v = e4[(size_t)i * (NN * 32)];
                acc.x += a * v.x; acc.y += a * v.y;
                acc.z += a * v.z; acc.w += a * v.w;
            }
        }
        red[g][d4] = acc;
    }

    // ---- C: ah[jj][k] = sum_i adj[i][jj]*h[b,i,k], threads < 256 ----
    const int k = t & 127, jl = (t >> 7) & 1;
    if (t < 256) {
        float a0 = 0.f, a1 = 0.f;
        const float* __restrict__ hp = h + (size_t)b * NN * DD + k;
        #pragma unroll 8
        for (int m = 0; m < 32; ++m) {
            const float4 aA = *(const float4*)&adj_s[jl][4 * m];       // LDS broadcast
            const float4 aB = *(const float4*)&adj_s[jl + 2][4 * m];
            const float h0 = hp[(size_t)(4 * m + 0) * DD];
            const float h1 = hp[(size_t)(4 * m + 1) * DD];
            const float h2 = hp[(size_t)(4 * m + 2) * DD];
            const float h3 = hp[(size_t)(4 * m + 3) * DD];
            a0 += aA.x * h0 + aA.y * h1 + aA.z * h2 + aA.w * h3;
            a1 += aB.x * h0 + aB.y * h1 + aB.z * h2 + aB.w * h3;
        }
        ah_s[jl][k] = a0;
        ah_s[jl + 2][k] = a1;
    }
    __syncthreads();

    // reduce red -> es_s (threads < 128): es_s[jj] = sum over 4 i-quarters
    if (t < 128) {
        const int jj = t >> 5, l = t & 31;
        float4 s = red[jj][l];
        #pragma unroll
        for (int q = 1; q < 4; ++q) {
            const float4 v = red[jj + 4 * q][l];
            s.x += v.x; s.y += v.y; s.z += v.z; s.w += v.w;
        }
        *(float4*)&es_s[jj][4 * l] = s;
    }
    __syncthreads();

    // ---- D: msum[jj][k] for jj = jl, jl+2 (threads < 256) ----
    if (t < 256) {
        float pa0 = 0, pa1 = 0, ph0 = 0, ph1 = 0, pe0 = 0, pe1 = 0;
        const float4* __restrict__ w1p = (const float4*)WmT4 + k;
        const float4* __restrict__ w2p = w1p + 32 * 128;
        const float4* __restrict__ w3p = w1p + 64 * 128;
        #pragma unroll 4
        for (int q = 0; q < 32; ++q) {
            const float4 w1 = w1p[q * 128];
            const float4 w2 = w2p[q * 128];
            const float4 w3 = w3p[q * 128];
            const float4 ahA = *(const float4*)&ah_s[jl][4 * q];
            const float4 ahB = *(const float4*)&ah_s[jl + 2][4 * q];
            const float4 hA  = *(const float4*)&h_s[jl][4 * q];
            const float4 hB  = *(const float4*)&h_s[jl + 2][4 * q];
            const float4 eA  = *(const float4*)&es_s[jl][4 * q];
            const float4 eB  = *(const float4*)&es_s[jl + 2][4 * q];
            pa0 += ahA.x * w1.x + ahA.y * w1.y + ahA.z * w1.z + ahA.w * w1.w;
            pa1 += ahB.x * w1.x + ahB.y * w1.y + ahB.z * w1.z + ahB.w * w1.w;
            ph0 += hA.x * w2.x + hA.y * w2.y + hA.z * w2.z + hA.w * w2.w;
            ph1 += hB.x * w2.x + hB.y * w2.y + hB.z * w2.z + hB.w * w2.w;
            pe0 += eA.x * w3.x + eA.y * w3.y + eA.z * w3.z + eA.w * w3.w;
            pe1 += eB.x * w3.x + eB.y * w3.y + eB.z * w3.z + eB.w * w3.w;
        }
        const float bmk = bm[k];
        ms_s[jl][k]     = pa0 + pe0 + deg_s[jl]     * (ph0 + bmk);
        ms_s[jl + 2][k] = pa1 + pe1 + deg_s[jl + 2] * (ph1 + bmk);
    }
    __syncthreads();

    // ---- E: out = h·WuA^T + msum·WuB^T + bu (threads < 256) ----
    if (t < 256) {
        float o0 = 0, o1 = 0;
        const float4* __restrict__ wap = (const float4*)WuT4 + k;
        const float4* __restrict__ wbp = wap + 32 * 128;
        #pragma unroll 4
        for (int q = 0; q < 32; ++q) {
            const float4 wa = wap[q * 128];
            const float4 wb = wbp[q * 128];
            const float4 hA = *(const float4*)&h_s[jl][4 * q];
            const float4 hB = *(const float4*)&h_s[jl + 2][4 * q];
            const float4 mA = *(const float4*)&ms_s[jl][4 * q];
            const float4 mB = *(const float4*)&ms_s[jl + 2][4 * q];
            o0 += hA.x * wa.x + hA.y * wa.y + hA.z * wa.z + hA.w * wa.w
                + mA.x * wb.x + mA.y * wb.y + mA.z * wb.z + mA.w * wb.w;
            o1 += hB.x * wa.x + hB.y * wa.y + hB.z * wa.z + hB.w * wa.w
                + mB.x * wb.x + mB.y * wb.y + mB.z * wb.z + mB.w * wb.w;
        }
        const float buk = bu[k];
        out[(size_t)(b * NN + jbase + jl) * DD + k]     = o0 + buk;
        out[(size_t)(b * NN + jbase + jl + 2) * DD + k] = o1 + buk;
    }
}

extern "C" void kernel_launch(void* const* d_in, const int* in_sizes, int n_in,
                              void* d_out, int out_size, void* d_ws, size_t ws_size,
                              hipStream_t stream) {
    const float* h   = (const float*)d_in[0];
    const float* adj = (const float*)d_in[1];
    const float* e   = (const float*)d_in[2];
    const float* Wm  = (const float*)d_in[3];
    const float* bm  = (const float*)d_in[4];
    const float* Wu  = (const float*)d_in[5];
    const float* bu  = (const float*)d_in[6];
    float* out  = (float*)d_out;
    float* WmT4 = (float*)d_ws;                // 384*128 floats
    float* WuT4 = WmT4 + 384 * 128;            // 256*128 floats (320 KB total)

    wtrans_kernel<<<320, 256, 0, stream>>>(Wm, Wu, WmT4, WuT4);
    mpnn_kernel<<<BB * (NN / 4), 512, 0, stream>>>(h, adj, e, WmT4, bm, WuT4, bu, out);
}